// Round 5
// baseline (249.733 us; speedup 1.0000x reference)
//
#include <hip/hip_runtime.h>

#define N_DIM 8192   // rows of features / columns of w / output length
#define K_DIM 512    // inner dim of features @ E
#define D_DIM 4096   // columns of E / rows of w

typedef __bf16 bf16x8 __attribute__((ext_vector_type(8)));
typedef float  f32x16 __attribute__((ext_vector_type(16)));
typedef unsigned short u16x8 __attribute__((ext_vector_type(8)));

__device__ __forceinline__ unsigned short f2bf(float f) {
    union { float f; unsigned int u; } v; v.f = f;
    unsigned int r = v.u + 0x7FFF + ((v.u >> 16) & 1);   // RNE
    return (unsigned short)(r >> 16);
}

// ---------------------------------------------------------------------------
// Kernel 1: E [512][4096] f32  ->  ET [4096][512] bf16 (k-contiguous rows)
// ---------------------------------------------------------------------------
__global__ __launch_bounds__(256) void transpose_E(const float* __restrict__ E,
                                                   unsigned short* __restrict__ ET) {
    __shared__ float tile[64][65];
    const int d0 = blockIdx.x * 64;
    const int k0 = blockIdx.y * 64;
    const int tid = threadIdx.x;
    const int r  = tid / 16;          // 0..15
    const int c4 = (tid % 16) * 4;    // 0..60
#pragma unroll
    for (int p = 0; p < 4; ++p) {
        int k = p * 16 + r;
        float4 v = *reinterpret_cast<const float4*>(E + (size_t)(k0 + k) * D_DIM + d0 + c4);
        tile[k][c4 + 0] = v.x; tile[k][c4 + 1] = v.y;
        tile[k][c4 + 2] = v.z; tile[k][c4 + 3] = v.w;
    }
    __syncthreads();
#pragma unroll
    for (int p = 0; p < 4; ++p) {
        int d = p * 16 + r;
        ushort4 o;
        o.x = f2bf(tile[c4 + 0][d]);
        o.y = f2bf(tile[c4 + 1][d]);
        o.z = f2bf(tile[c4 + 2][d]);
        o.w = f2bf(tile[c4 + 3][d]);
        *reinterpret_cast<ushort4*>(ET + (size_t)(d0 + d) * K_DIM + k0 + c4) = o;
    }
}

// ---------------------------------------------------------------------------
// Kernel 2: F [8192][512] f32 -> FB bf16, same layout (k-contiguous rows)
// ---------------------------------------------------------------------------
__global__ __launch_bounds__(256) void convert_F(const float* __restrict__ F,
                                                 unsigned short* __restrict__ FB) {
    const int idx8 = (blockIdx.x * 256 + threadIdx.x) * 8;
    float4 a = *reinterpret_cast<const float4*>(F + idx8);
    float4 b = *reinterpret_cast<const float4*>(F + idx8 + 4);
    u16x8 o;
    o[0] = f2bf(a.x); o[1] = f2bf(a.y); o[2] = f2bf(a.z); o[3] = f2bf(a.w);
    o[4] = f2bf(b.x); o[5] = f2bf(b.y); o[6] = f2bf(b.z); o[7] = f2bf(b.w);
    *reinterpret_cast<u16x8*>(FB + idx8) = o;
}

// ---------------------------------------------------------------------------
// Kernel 3: fused  out[n] = sum_d (F@E + b)[n,d] * w[d,n], computed as y^T.
// R5: block tile 128(d) x 256(n), BK=64, 4 waves (2x2), wave tile 64x128,
// acc[2][4] of 32x32x16 MFMA -> per ks-step 6 ds_read_b128 : 8 MFMA
// (was 4:4 = 1.5 read:mfma; now 1.125). Staging 512->393 MB total.
// XCD rectangle: 8 n-tiles x 16 d-tiles per XCD = 4 MB L2 working set.
// ---------------------------------------------------------------------------
__global__ __launch_bounds__(256, 2) void gemm_fused(const unsigned short* __restrict__ FB,
                                                     const float* __restrict__ W,
                                                     const unsigned short* __restrict__ ET,
                                                     const float* __restrict__ B,
                                                     float* __restrict__ out) {
    __shared__ unsigned short Ash[2 * 128 * 32];  // ET tile: 128 d-rows, 2 k-panels (16 KB)
    __shared__ unsigned short Bsh[2 * 256 * 32];  // FB tile: 256 n-rows, 2 k-panels (32 KB)

    const int tid  = threadIdx.x;
    const int wave = tid >> 6;
    const int lane = tid & 63;
    const int wy   = wave >> 1;     // d-direction wave coord (0..1) -> 64 d
    const int wx   = wave & 1;      // n-direction wave coord (0..1) -> 128 n
    const int l31  = lane & 31;
    const int half = lane >> 5;

    // --- XCD-rectangle swizzle (bijection on 32x32 tile grid, 1024 blocks) ---
    const int f     = blockIdx.x;          // dispatch order; XCD = f % 8
    const int xcd   = f & 7;
    const int s     = f >> 3;              // 0..127 within XCD
    const int ntile = (xcd & 3) * 8 + (s & 7);     // 0..31 (256-wide n tiles)
    const int dtile = (xcd >> 2) * 16 + (s >> 3);  // 0..31 (128-wide d tiles)
    const int n0 = ntile * 256;
    const int d0 = dtile * 128;

    f32x16 acc[2][4] = {};   // [mi=d][ni=n]

    // staging: one global_load_lds(16B) covers 16 rows x 64 B
    const int srow   = lane >> 2;                               // 0..15
    const int schunk = (((lane & 3) ^ ((srow >> 1) & 3)) * 8);  // swizzled chunk (shorts)

    for (int kt = 0; kt < K_DIM / 64; ++kt) {
        const int kb = kt * 64;
#pragma unroll
        for (int p = 0; p < 2; ++p) {
            // A: 8 insts (128 rows), 2 per wave
#pragma unroll
            for (int jj = 0; jj < 2; ++jj) {
                const int j = wave * 2 + jj;   // 0..7
                const unsigned short* ga =
                    ET + (size_t)(d0 + j * 16 + srow) * K_DIM + kb + p * 32 + schunk;
                __builtin_amdgcn_global_load_lds(
                    (const __attribute__((address_space(1))) void*)ga,
                    (__attribute__((address_space(3))) void*)(Ash + p * 4096 + j * 512),
                    16, 0, 0);
            }
            // B: 16 insts (256 rows), 4 per wave
#pragma unroll
            for (int jj = 0; jj < 4; ++jj) {
                const int j = wave * 4 + jj;   // 0..15
                const unsigned short* gb =
                    FB + (size_t)(n0 + j * 16 + srow) * K_DIM + kb + p * 32 + schunk;
                __builtin_amdgcn_global_load_lds(
                    (const __attribute__((address_space(1))) void*)gb,
                    (__attribute__((address_space(3))) void*)(Bsh + p * 8192 + j * 512),
                    16, 0, 0);
            }
        }
        __syncthreads();

#pragma unroll
        for (int ks = 0; ks < 4; ++ks) {
            const int p = ks >> 1;
            const int c = (ks & 1) * 2 + half;   // 16B chunk index within row
            bf16x8 af[2], bf[4];
#pragma unroll
            for (int mi = 0; mi < 2; ++mi) {
                const int R = wy * 64 + mi * 32 + l31;         // 0..127
                const int slot = c ^ ((R >> 1) & 3);
                af[mi] = *reinterpret_cast<const bf16x8*>(
                    Ash + p * 4096 + R * 32 + slot * 8);
            }
#pragma unroll
            for (int ni = 0; ni < 4; ++ni) {
                const int R = wx * 128 + ni * 32 + l31;        // 0..255
                const int slot = c ^ ((R >> 1) & 3);
                bf[ni] = *reinterpret_cast<const bf16x8*>(
                    Bsh + p * 8192 + R * 32 + slot * 8);
            }
#pragma unroll
            for (int mi = 0; mi < 2; ++mi)
#pragma unroll
                for (int ni = 0; ni < 4; ++ni)
                    acc[mi][ni] = __builtin_amdgcn_mfma_f32_32x32x16_bf16(
                        af[mi], bf[ni], acc[mi][ni], 0, 0, 0);
        }
        __syncthreads();
    }

    // --- epilogue: C layout 32x32: col(n)=lane&31, row(d)=(reg&3)+8*(reg>>2)+4*half
    // W read exactly once device-wide -> non-temporal.
    const int nb = n0 + wx * 128;
    float part[4] = {0.f, 0.f, 0.f, 0.f};
#pragma unroll
    for (int mi = 0; mi < 2; ++mi) {
        const int dbase = d0 + wy * 64 + mi * 32 + 4 * half;
#pragma unroll
        for (int reg = 0; reg < 16; ++reg) {
            const int dd = dbase + (reg & 3) + 8 * (reg >> 2);
            const float bd = B[dd];
            const float* wr = W + (size_t)dd * N_DIM + nb;
#pragma unroll
            for (int ni = 0; ni < 4; ++ni)
                part[ni] += (acc[mi][ni][reg] + bd) *
                            __builtin_nontemporal_load(wr + ni * 32 + l31);
        }
    }
#pragma unroll
    for (int ni = 0; ni < 4; ++ni) {
        part[ni] += __shfl_xor(part[ni], 32);
        if (lane < 32)
            atomicAdd(out + nb + ni * 32 + l31, part[ni]);
    }
}

extern "C" void kernel_launch(void* const* d_in, const int* in_sizes, int n_in,
                              void* d_out, int out_size, void* d_ws, size_t ws_size,
                              hipStream_t stream) {
    const float* F = (const float*)d_in[0];   // features (N, K)
    const float* W = (const float*)d_in[1];   // w        (D, N)
    const float* E = (const float*)d_in[2];   // E        (K, D)
    const float* B = (const float*)d_in[3];   // b        (D,)
    float* out = (float*)d_out;               // (N,) f32

    unsigned short* ET = (unsigned short*)d_ws;                       // 4 MB
    unsigned short* FB = (unsigned short*)((char*)d_ws + (size_t)D_DIM * K_DIM * 2);  // 8 MB

    hipMemsetAsync(d_out, 0, (size_t)out_size * sizeof(float), stream);
    transpose_E<<<dim3(D_DIM / 64, K_DIM / 64), 256, 0, stream>>>(E, ET);
    convert_F<<<dim3(N_DIM * K_DIM / (256 * 8)), 256, 0, stream>>>(F, FB);
    gemm_fused<<<dim3((N_DIM / 256) * (D_DIM / 128)), 256, 0, stream>>>(FB, W, ET, B, out);
}